// Round 9
// baseline (1750.836 us; speedup 1.0000x reference)
//
#include <hip/hip_runtime.h>
#include <cstdint>
#include <cstddef>

typedef _Float16 f16x2 __attribute__((ext_vector_type(2)));
typedef _Float16 half4 __attribute__((ext_vector_type(4)));
typedef _Float16 half8 __attribute__((ext_vector_type(8)));
typedef float f32x4 __attribute__((ext_vector_type(4)));

static constexpr int BB = 64;    // batch
static constexpr int TT = 1024;  // time steps
static constexpr int FF = 512;   // input features
static constexpr int UU = 256;   // hidden units per direction
static constexpr int NZ = 1024;  // 4*UU gate width

static constexpr size_t LSTM_SHBYTES = 90112;   // force 1 block/CU (160KiB LDS pool)
static constexpr int HREP_STRIDE = 608;         // replica stride (bank-staggered)

__device__ __forceinline__ f16x2 bc16(unsigned int v) { return __builtin_bit_cast(f16x2, v); }

__device__ __forceinline__ void st_u32_rlx(unsigned int* p, unsigned int v)
{
    __hip_atomic_store(p, v, __ATOMIC_RELAXED, __HIP_MEMORY_SCOPE_AGENT);
}
__device__ __forceinline__ unsigned int ld_u32_rlx(const unsigned int* p)
{
    return __hip_atomic_load(p, __ATOMIC_RELAXED, __HIP_MEMORY_SCOPE_AGENT);
}

// Raw barrier: drains LDS ops only; leaves global loads (vmcnt) in flight.
__device__ __forceinline__ void bar_lgkm()
{
    asm volatile("s_waitcnt lgkmcnt(0)\n\ts_barrier" ::: "memory");
}

// quad (4-lane) sum via DPP quad_perm: xor1 = [1,0,3,2] = 0xB1, xor2 = [2,3,0,1] = 0x4E
__device__ __forceinline__ float qsum(float v)
{
    int b1 = __builtin_amdgcn_mov_dpp(__builtin_bit_cast(int, v), 0xB1, 0xf, 0xf, true);
    v += __builtin_bit_cast(float, b1);
    int b2 = __builtin_amdgcn_mov_dpp(__builtin_bit_cast(int, v), 0x4E, 0xf, 0xf, true);
    v += __builtin_bit_cast(float, b2);
    return v;
}

// ---------------------------------------------------------------------------
// Cast x fp32 -> f16 (flat)
// ---------------------------------------------------------------------------
__global__ __launch_bounds__(256) void enc_cast_x(
    const float* __restrict__ x, _Float16* __restrict__ x16, int n4)
{
    int stride = gridDim.x * 256;
    for (int i = blockIdx.x * 256 + threadIdx.x; i < n4; i += stride) {
        float4 v = ((const float4*)x)[i];
        half4 o;
        o.x = (_Float16)v.x; o.y = (_Float16)v.y;
        o.z = (_Float16)v.z; o.w = (_Float16)v.w;
        ((half4*)x16)[i] = o;
    }
}

// ---------------------------------------------------------------------------
// W [512,1024] fp32 -> WT [dir][1024][512] f16 (transposed)
// ---------------------------------------------------------------------------
__global__ __launch_bounds__(256) void enc_cast_wt(
    const float* __restrict__ Wf, const float* __restrict__ Wb,
    _Float16* __restrict__ WT)
{
    __shared__ float tile[64][65];
    const int t = threadIdx.x;
    const int k0 = blockIdx.x * 64;
    const int n0 = blockIdx.y * 64;
    const int d = blockIdx.z;
    const float* W = d ? Wb : Wf;
    _Float16* WTd = WT + (size_t)d * NZ * FF;
#pragma unroll
    for (int p = 0; p < 16; ++p) {
        int idx = p * 256 + t;
        int r = idx >> 6, c = idx & 63;
        tile[r][c] = W[(size_t)(k0 + r) * NZ + n0 + c];
    }
    __syncthreads();
#pragma unroll
    for (int p = 0; p < 16; ++p) {
        int idx = p * 256 + t;
        int r = idx >> 6, c = idx & 63;
        WTd[(size_t)(n0 + r) * FF + k0 + c] = (_Float16)tile[c][r];
    }
}

// ---------------------------------------------------------------------------
// Pack U: Upkr2[(d*128 + k2)*256 + j] = uint4 of 4 gate words;
// word g = { U_d[2*k2][g*256+j], U_d[2*k2+1][g*256+j] } as f16x2.
// ---------------------------------------------------------------------------
__global__ __launch_bounds__(256) void enc_pack_u16v2(
    const float* __restrict__ Uf, const float* __restrict__ Ub,
    uint4* __restrict__ Upkr2)
{
    int idx = blockIdx.x * 256 + threadIdx.x;     // 0 .. 65535
    if (idx >= 2 * 128 * 256) return;
    int d  = idx >> 15;
    int k2 = (idx >> 8) & 127;
    int j  = idx & 255;
    int k = 2 * k2;
    const float* Ud = d ? Ub : Uf;
    unsigned int w[4];
#pragma unroll
    for (int g = 0; g < 4; ++g) {
        f16x2 h;
        h.x = (_Float16)Ud[(size_t)k * NZ + g * 256 + j];
        h.y = (_Float16)Ud[(size_t)(k + 1) * NZ + g * 256 + j];
        w[g] = __builtin_bit_cast(unsigned int, h);
    }
    Upkr2[idx] = make_uint4(w[0], w[1], w[2], w[3]);
}

__global__ __launch_bounds__(256) void enc_zero(float* __restrict__ p, int n)
{
    int i = blockIdx.x * 256 + threadIdx.x;
    if (i < n) p[i] = 0.f;
}

// ---------------------------------------------------------------------------
// MFMA GEMM: xz16[r, n] = x16_row(r) . W_d[:, n] + b_d[n]   (unchanged)
// ---------------------------------------------------------------------------
__global__ __launch_bounds__(256) void enc_gemm16(
    const _Float16* __restrict__ x16, const _Float16* __restrict__ WT,
    const float* __restrict__ bf, const float* __restrict__ bb,
    _Float16* __restrict__ xz16, int c0, int CT)
{
    __shared__ __align__(16) _Float16 Ash[128][40];
    __shared__ __align__(16) _Float16 Bsh[128][40];

    const int t = threadIdx.x;
    const int r0 = blockIdx.x * 128;
    const int n0 = blockIdx.y * 128;
    const int MperD = BB * CT;
    const int d = r0 / MperD;

    const int srow = t >> 2;
    const int koff = (t & 3) * 8;

    auto xrowptr = [&](int r) -> const _Float16* {
        int rd = r - d * MperD;
        int b = rd / CT;
        int tl = rd - b * CT;
        int tsrc = d ? (TT - 1 - (c0 + tl)) : (c0 + tl);
        return x16 + ((size_t)b * TT + tsrc) * FF;
    };
    const _Float16* ap0 = xrowptr(r0 + srow);
    const _Float16* ap1 = xrowptr(r0 + 64 + srow);
    const _Float16* wp0 = WT + (size_t)(d * NZ + n0 + srow) * FF;
    const _Float16* wp1 = wp0 + (size_t)64 * FF;

    const int lane = t & 63;
    const int w = t >> 6;
    const int wm = w >> 1, wn = w & 1;
    const int l15 = lane & 15;
    const int kq = (lane >> 4) * 8;

    f32x4 acc[4][4];
#pragma unroll
    for (int i = 0; i < 4; ++i)
#pragma unroll
        for (int j = 0; j < 4; ++j) acc[i][j] = (f32x4)0.f;

    for (int ks = 0; ks < FF / 32; ++ks) {
        const int k0 = ks * 32;
        uint4 av0 = *(const uint4*)(ap0 + k0 + koff);
        uint4 av1 = *(const uint4*)(ap1 + k0 + koff);
        uint4 bv0 = *(const uint4*)(wp0 + k0 + koff);
        uint4 bv1 = *(const uint4*)(wp1 + k0 + koff);
        __syncthreads();
        *(uint4*)&Ash[srow][koff]      = av0;
        *(uint4*)&Ash[64 + srow][koff] = av1;
        *(uint4*)&Bsh[srow][koff]      = bv0;
        *(uint4*)&Bsh[64 + srow][koff] = bv1;
        __syncthreads();

        half8 af[4], bfr[4];
#pragma unroll
        for (int mf = 0; mf < 4; ++mf)
            af[mf] = *(const half8*)&Ash[wm * 64 + mf * 16 + l15][kq];
#pragma unroll
        for (int nf = 0; nf < 4; ++nf)
            bfr[nf] = *(const half8*)&Bsh[wn * 64 + nf * 16 + l15][kq];
#pragma unroll
        for (int mf = 0; mf < 4; ++mf)
#pragma unroll
            for (int nf = 0; nf < 4; ++nf)
                acc[mf][nf] = __builtin_amdgcn_mfma_f32_16x16x32_f16(
                    af[mf], bfr[nf], acc[mf][nf], 0, 0, 0);
    }

    const float* bd = d ? bb : bf;
    const int rbase = r0 + wm * 64;
    const int cbase = n0 + wn * 64;
#pragma unroll
    for (int nf = 0; nf < 4; ++nf) {
        const int cc = cbase + nf * 16 + l15;
        const float bia = bd[cc];
#pragma unroll
        for (int mf = 0; mf < 4; ++mf) {
#pragma unroll
            for (int rg = 0; rg < 4; ++rg) {
                int rr = rbase + mf * 16 + (lane >> 4) * 4 + rg;
                xz16[(size_t)rr * NZ + cc] = (_Float16)(acc[mf][nf][rg] + bia);
            }
        }
    }
}

// ---------------------------------------------------------------------------
// 16-k2 dot with compile-time U-register base (rule #20: no runtime indexing)
// ---------------------------------------------------------------------------
template <int MBASE>
__device__ __forceinline__ void dot16(const uint4 (&ureg)[32], const char* hptr,
                                      float& a0, float& a1, float& a2, float& a3)
{
#pragma unroll
    for (int r = 0; r < 4; ++r) {
        uint4 hq = *(const uint4*)(hptr + r * 16);
#pragma unroll
        for (int e = 0; e < 4; ++e) {
            f16x2 hw = bc16((&hq.x)[e]);
            const uint4 uv = ureg[MBASE + r * 4 + e];
            a0 = __builtin_amdgcn_fdot2(hw, bc16(uv.x), a0, false);
            a1 = __builtin_amdgcn_fdot2(hw, bc16(uv.y), a1, false);
            a2 = __builtin_amdgcn_fdot2(hw, bc16(uv.z), a2, false);
            a3 = __builtin_amdgcn_fdot2(hw, bc16(uv.w), a3, false);
        }
    }
}

// ---------------------------------------------------------------------------
// Quad-split recurrence: 256 blocks = (jh = beta>>7, chain = beta&127).
// t = jl*4 + q: lane q owns k in [q*32,(q+1)*32) U [128+q*32, 128+(q+1)*32)
// for ALL 4 gates of unit j = jh*128+jl  (32 uint4 of U in VGPRs).
// ph1: waves 6-7 finalize partner-h arrival (prev step's tag, proven
//      protocol); ALL waves dot own-half subquarter (lane-uniform).
// bar1. ph2: all waves dot partner-half; xz inject on lane q (once per gate
// after quad-sum); DPP quad reduce -> every lane has full z; gates duplicated
// x4; q==0 publishes tagged h + writes out; own h written to replica jl>>5.
// bar2. 2 barriers/step, no parts-LDS, all waves busy in every dot phase.
// h replicas: 4 x 512B, stride 608B -> per-instruction banks {0,8,16,24}+4r.
// ---------------------------------------------------------------------------
__device__ __forceinline__ float sigm_f(float xv)
{
    return 1.0f / (1.0f + __expf(-xv));
}
__device__ __forceinline__ float tanh_f(float xv)
{
    return 2.0f / (1.0f + __expf(-2.0f * xv)) - 1.0f;
}

__global__ __launch_bounds__(512, 2) void enc_lstm_quad(
    const _Float16* __restrict__ xz16, const uint4* __restrict__ Upkr2,
    float* __restrict__ hstate, float* __restrict__ cstate,
    unsigned int* __restrict__ hbuf,
    float* __restrict__ out, int c0, int CT)
{
    extern __shared__ char smem2[];          // 4 replicas x 608 B

    const int t  = threadIdx.x;
    const int q  = t & 3;
    const int jl = t >> 2;                   // 0..127
    const int w  = t >> 6;                   // wave 0..7
    const int beta = blockIdx.x;
    const int jh = beta >> 7;
    const int c  = beta & 127;
    const int d  = c >> 6;
    const int b  = c & 63;
    const int j  = jh * 128 + jl;
    const int partner = beta ^ 128;

    // ---- persistent U: 32 uint4 (k-subquarters of both halves x 4 gates) ----
    const uint4* Uq = Upkr2 + (size_t)d * 128 * 256 + j;
    uint4 ureg[32];
#pragma unroll
    for (int m = 0; m < 16; ++m)
        ureg[m] = Uq[(size_t)(q * 16 + m) * 256];          // k-half 0
#pragma unroll
    for (int m = 0; m < 16; ++m)
        ureg[16 + m] = Uq[(size_t)(64 + q * 16 + m) * 256]; // k-half 1

    // ---- state init ----
    float cr = cstate[(size_t)c * UU + j];   // duplicated across quad
    float hn = 0.f;
    if (t < 256) {
        _Float16 hv = (_Float16)hstate[(size_t)c * UU + t];
        // h element t lives in replica ((t&127)>>5) at position t
        *(unsigned short*)(smem2 + ((t & 127) >> 5) * HREP_STRIDE + t * 2) =
            __builtin_bit_cast(unsigned short, hv);
    }
    __syncthreads();

    const _Float16* xzrow = xz16 + (size_t)c * CT * NZ;
    float* outb = out + (size_t)b * TT * (2 * UU) + d * UU;

    // h-read pointers (fixed): replica q, uint4 idx = half*16 + q*4
    const char* hp0 = smem2 + q * HREP_STRIDE + (0 * 16 + q * 4) * 16;
    const char* hp1 = smem2 + q * HREP_STRIDE + (1 * 16 + q * 4) * 16;

    // arrival duty (waves 6-7): lane al handles partner unit al
    const int al = t - 384;                         // valid when w >= 6
    const int pj = (1 - jh) * 128 + (al & 127);     // masked for safety
    unsigned int pref = 0;

    for (int tl = 0; tl < CT; ++tl) {
        const int step = c0 + tl + 1;   // h produced this iteration
        const int htag = c0 + tl;       // partner h consumed this iteration

        // xz for this step (global load, consumed after ph2 dot: well covered)
        const unsigned short xq =
            *((const unsigned short*)(xzrow + (size_t)tl * NZ) + q * 256 + j);

        // ---- ph1: arrival (waves 6-7) + own-half dot (all waves) ----
        if (w >= 6 && tl > 0) {
            const unsigned int* pp =
                &hbuf[((size_t)(htag & 1) * 256 + partner) * 128 + al];
            unsigned int v = pref;
            while ((v >> 16) != (unsigned int)htag)
                v = ld_u32_rlx(pp);
            *(unsigned short*)(smem2 + (al >> 5) * HREP_STRIDE + pj * 2) =
                (unsigned short)(v & 0xffffu);
        }

        float a0 = 0.f, a1 = 0.f, a2 = 0.f, a3 = 0.f;
        if (jh == 0) dot16<0>(ureg, hp0, a0, a1, a2, a3);
        else         dot16<16>(ureg, hp1, a0, a1, a2, a3);
        bar_lgkm();                                // bar1: partner h visible

        // ---- ph2: partner-half dot ----
        if (jh == 0) dot16<16>(ureg, hp1, a0, a1, a2, a3);
        else         dot16<0>(ureg, hp0, a0, a1, a2, a3);

        // inject xz on lane q into accumulator q (summed once by quad reduce)
        {
            float xv = (float)__builtin_bit_cast(_Float16, xq);
            a0 += (q == 0) ? xv : 0.f;
            a1 += (q == 1) ? xv : 0.f;
            a2 += (q == 2) ? xv : 0.f;
            a3 += (q == 3) ? xv : 0.f;
        }
        // quad reduce: every lane gets full z for its jl
        float zi = qsum(a0), zf = qsum(a1), zg = qsum(a2), zo = qsum(a3);

        // gates (duplicated across quad — identical deterministic results)
        float ig = sigm_f(zi), fg = sigm_f(zf), gg = tanh_f(zg), og = sigm_f(zo);
        cr = fg * cr + ig * gg;
        hn = og * tanh_f(cr);
        _Float16 h16 = (_Float16)hn;
        unsigned short hbits = __builtin_bit_cast(unsigned short, h16);

        if (q == 0) {
            // tagged publish first (partner consumes next iteration)
            st_u32_rlx(&hbuf[((size_t)(step & 1) * 256 + beta) * 128 + jl],
                       ((unsigned int)step << 16) | (unsigned int)hbits);
            int tsrc = d ? (TT - 1 - (c0 + tl)) : (c0 + tl);
            outb[(size_t)tsrc * (2 * UU) + j] = hn;
            // own-half h -> replica jl>>5 at position j
            *(unsigned short*)(smem2 + (jl >> 5) * HREP_STRIDE + j * 2) = hbits;
        }
        if (w >= 6) {
            // prefetch sample for next iteration's htag (= step)
            pref = ld_u32_rlx(
                &hbuf[((size_t)(step & 1) * 256 + partner) * 128 + al]);
        }
        bar_lgkm();                                // bar2: own h visible
    }

    if (q == 0) {
        hstate[(size_t)c * UU + j] = hn;
        cstate[(size_t)c * UU + j] = cr;
    }
}

// ---------------------------------------------------------------------------
// Final h/c copy into d_out tail sections
// ---------------------------------------------------------------------------
__global__ __launch_bounds__(256) void enc_final(
    const float* __restrict__ hstate, const float* __restrict__ cstate,
    float* __restrict__ out)
{
    int idx = blockIdx.x * 256 + threadIdx.x;
    if (idx >= 2 * BB * UU) return;
    int d = idx / (BB * UU);
    int rem = idx - d * (BB * UU);
    int b = rem / UU;
    int j = rem - b * UU;
    size_t OUT_H = (size_t)BB * TT * (2 * UU);
    size_t HSZ = (size_t)BB * (2 * UU);
    out[OUT_H + (size_t)b * (2 * UU) + d * UU + j] = hstate[idx];
    out[OUT_H + HSZ + (size_t)b * (2 * UU) + d * UU + j] = cstate[idx];
}

// ---------------------------------------------------------------------------
extern "C" void kernel_launch(void* const* d_in, const int* in_sizes, int n_in,
                              void* d_out, int out_size, void* d_ws, size_t ws_size,
                              hipStream_t stream)
{
    const float* x  = (const float*)d_in[0];
    const float* Wf = (const float*)d_in[1];
    const float* Uf = (const float*)d_in[2];
    const float* bf = (const float*)d_in[3];
    const float* Wb = (const float*)d_in[4];
    const float* Ub = (const float*)d_in[5];
    const float* bb = (const float*)d_in[6];
    float* out = (float*)d_out;

    const size_t x16_bytes   = (size_t)BB * TT * FF * 2;             // 64 MiB
    const size_t wt_bytes    = (size_t)2 * NZ * FF * 2;              // 2 MiB
    const size_t upk_bytes   = (size_t)2 * 128 * 256 * sizeof(uint4);// 1 MiB
    const size_t state_bytes = (size_t)2 * BB * UU * sizeof(float);  // 128 KiB each
    const size_t hbuf_bytes  = (size_t)2 * 256 * 128 * 4;            // 256 KiB
    const size_t fixed = x16_bytes + wt_bytes + upk_bytes + 2 * state_bytes
                       + hbuf_bytes;

    int CT = TT;
    while (CT > 8) {
        size_t need = fixed + (size_t)2 * BB * CT * NZ * 2;
        if (need <= ws_size) break;
        CT >>= 1;
    }

    char* wsb = (char*)d_ws;
    _Float16* x16 = (_Float16*)wsb;
    _Float16* WT  = (_Float16*)(wsb + x16_bytes);
    uint4* Upkr2  = (uint4*)(wsb + x16_bytes + wt_bytes);
    float* hstate = (float*)(wsb + x16_bytes + wt_bytes + upk_bytes);
    float* cstate = hstate + 2 * BB * UU;
    unsigned int* hbuf = (unsigned int*)(wsb + x16_bytes + wt_bytes + upk_bytes
                                         + 2 * state_bytes);
    _Float16* xz16 = (_Float16*)(wsb + fixed);

    (void)hipFuncSetAttribute(reinterpret_cast<const void*>(enc_lstm_quad),
                              hipFuncAttributeMaxDynamicSharedMemorySize,
                              (int)LSTM_SHBYTES);

    enc_cast_x<<<4096, 256, 0, stream>>>(x, x16, BB * TT * FF / 4);
    enc_cast_wt<<<dim3(8, 16, 2), 256, 0, stream>>>(Wf, Wb, WT);
    enc_pack_u16v2<<<(2 * 128 * 256 + 255) / 256, 256, 0, stream>>>(Uf, Ub, Upkr2);
    enc_zero<<<(2 * 2 * BB * UU + 255) / 256, 256, 0, stream>>>(hstate, 2 * 2 * BB * UU);

    for (int c0 = 0; c0 < TT; c0 += CT) {
        dim3 ggrid((2 * BB * CT) / 128, NZ / 128);
        enc_gemm16<<<ggrid, 256, 0, stream>>>(x16, WT, bf, bb, xz16, c0, CT);
        enc_lstm_quad<<<256, 512, LSTM_SHBYTES, stream>>>(
            xz16, Upkr2, hstate, cstate, hbuf, out, c0, CT);
    }
    enc_final<<<(2 * BB * UU + 255) / 256, 256, 0, stream>>>(hstate, cstate, out);
}